// Round 3
// baseline (251.909 us; speedup 1.0000x reference)
//
#include <hip/hip_runtime.h>
#include <hip/hip_bf16.h>

typedef __attribute__((ext_vector_type(8))) short    short8;
typedef __attribute__((ext_vector_type(4))) short    short4v;
typedef __attribute__((ext_vector_type(4))) float    float4v;
typedef __attribute__((ext_vector_type(2))) unsigned uint2v;
typedef __attribute__((ext_vector_type(4))) unsigned uint4v;

// QK^T: S^T tile = K(16x32) * Q^T(32x16), both frags row-major [pos][d]
#define MFMA_QK(A,B,C) __builtin_amdgcn_mfma_f32_16x16x32_bf16(A,B,C,0,0,0)
// PV: K=16 variant -- B-frag layout (n=lane&15, k=quad*4+jj) == QK C/D layout: zero-shuffle P feed
#define MFMA_PV(A,B,C) __builtin_amdgcn_mfma_f32_16x16x16bf16_1k(A,B,C,0,0,0)

#define N_ 4096
#define D_ 64
#define W_ 128
// 0.125 (D^-0.5) * log2(e): folded into Q; softmax runs in base-2, no max-subtract
#define QSCALE 0.18033688011112042f

// pack two fp32 -> bf16 pair (a low). +0x8000 round-half-up: 2 add + 1 perm
static __device__ __forceinline__ unsigned pk2(float a, float b) {
  unsigned ua = __float_as_uint(a) + 0x8000u;
  unsigned ub = __float_as_uint(b) + 0x8000u;
  return __builtin_amdgcn_perm(ub, ua, 0x07060302u);
}
static __device__ __forceinline__ void rope_sc(float rev, float& sn, float& cs) {
  float fr = __builtin_amdgcn_fractf(rev);     // v_sin/v_cos take revolutions
  sn = __builtin_amdgcn_sinf(fr);
  cs = __builtin_amdgcn_cosf(fr);
}
static __device__ __forceinline__ float invfreq_rev(int idx) {
  // 10000^(-idx/32) / (2*pi);  log2(10000)/32 = 0.41524101186092034
  return __builtin_amdgcn_exp2f(-0.41524101186092034f * (float)idx) * 0.15915494309189535f;
}

__global__ __launch_bounds__(256, 3)
void la_fused(const float* __restrict__ qg, const float* __restrict__ kg,
              const float* __restrict__ vg, float* __restrict__ outg)
{
  // K rows stride 72 shorts: b128 frag reads = uniform 8 words/bank (optimal)
  __shared__ __attribute__((aligned(16))) short Kl[256][72];
  // V^T HALF buffer (j-chunks of 4, 32 chunks = 128 keys), reused for both halves
  __shared__ __attribute__((aligned(16))) short Vt[32][68][4];
  // total LDS 54,272 B -> 3 blocks/CU

  const int blk  = blockIdx.x;
  const int w    = blk & 31;
  const int bh   = blk >> 5;
  const int base = bh * (N_ * D_);
  const int tid  = threadIdx.x;
  const int lane = tid & 63;
  const int wv   = tid >> 6;        // wave 0..3 owns query rows wv*32..wv*32+31
  const int il   = lane & 15;
  const int qd   = lane >> 4;

  // ---------------- phase 1: stage K (RoPE'd bf16, full 256 rows) ----------------
  {
    const float* kb = kg + base;
    const int d0 = (tid & 7) << 2;           // fixed per thread across iters
    float fr4[4];
#pragma unroll
    for (int dd = 0; dd < 4; ++dd) fr4[dd] = invfreq_rev(d0 + dd);
#pragma unroll
    for (int it = 0; it < 8; ++it) {
      int j = it * 32 + (tid >> 3);          // key row 0..255
      int g = w * W_ - W_ + j;
      uint2v w0, w1;
      if (g < 0) {                           // look_around pads AFTER rope: exact -1.0
        w0 = uint2v{0xBF80BF80u, 0xBF80BF80u}; w1 = w0;
      } else {
        float4v a = *(const float4v*)(kb + g * D_ + d0);
        float4v b = *(const float4v*)(kb + g * D_ + d0 + 32);
        const float t = (float)g;
        float lo[4], hi[4];
#pragma unroll
        for (int dd = 0; dd < 4; ++dd) {
          float sn, cs; rope_sc(t * fr4[dd], sn, cs);
          lo[dd] = a[dd] * cs - b[dd] * sn;
          hi[dd] = b[dd] * cs + a[dd] * sn;
        }
        w0 = uint2v{ pk2(lo[0], lo[1]), pk2(lo[2], lo[3]) };
        w1 = uint2v{ pk2(hi[0], hi[1]), pk2(hi[2], hi[3]) };
      }
      *(uint2v*)&Kl[j][d0]      = w0;
      *(uint2v*)&Kl[j][d0 + 32] = w1;
    }
  }

  // -------- stage V^T half 1 (keys 0..127) + prefetch half 2 (128..255) to regs ----
  uint2v V2r[2][4];
  {
    const float* vb = vg + base;
    const int m  = tid & 15;
    const int d0 = m << 2;
#pragma unroll
    for (int pv = 0; pv < 4; ++pv) {
      int j0 = ((tid >> 4) + pv * 16) << 2;  // 4-row block; pv<2 => j0<128
      int g0 = w * W_ - W_ + j0;
      float vv[4][4];
      if (pv < 2 && g0 < 0) {
#pragma unroll
        for (int rr = 0; rr < 4; ++rr)
#pragma unroll
          for (int cc = 0; cc < 4; ++cc) vv[rr][cc] = -1.0f;
      } else {
#pragma unroll
        for (int rr = 0; rr < 4; ++rr) {
          float4v r = *(const float4v*)(vb + (g0 + rr) * D_ + d0);
          vv[rr][0]=r[0]; vv[rr][1]=r[1]; vv[rr][2]=r[2]; vv[rr][3]=r[3];
        }
      }
#pragma unroll
      for (int dd = 0; dd < 4; ++dd) {
        int cc = (dd + m) & 3;               // lane-rotated column order: spreads banks
        uint2v pw = uint2v{ pk2(vv[0][cc], vv[1][cc]), pk2(vv[2][cc], vv[3][cc]) };
        if (pv < 2) *(uint2v*)&Vt[j0 >> 2][d0 + cc][0] = pw;
        else        V2r[pv - 2][dd] = pw;    // held in regs until PV half 2
      }
    }
  }

  // ---------------- Q fragments (RoPE'd, pre-scaled) ----------------
  short8 qf[2][2];
  {
    float fr8[8];
#pragma unroll
    for (int jj = 0; jj < 8; ++jj) fr8[jj] = invfreq_rev(qd * 8 + jj);
#pragma unroll
    for (int ii = 0; ii < 2; ++ii) {
      const int n = w * W_ + wv * 32 + ii * 16 + il;
      const float* qr = qg + base + n * D_ + qd * 8;
      float4v x0 = *(const float4v*)(qr);
      float4v x1 = *(const float4v*)(qr + 4);
      float4v y0 = *(const float4v*)(qr + 32);
      float4v y1 = *(const float4v*)(qr + 36);
      const float t = (float)n;
      float lo[8], hi[8];
#pragma unroll
      for (int jj = 0; jj < 8; ++jj) {
        float xx = ((jj < 4) ? x0[jj & 3] : x1[jj & 3]) * QSCALE;
        float yy = ((jj < 4) ? y0[jj & 3] : y1[jj & 3]) * QSCALE;
        float sn, cs; rope_sc(t * fr8[jj], sn, cs);
        lo[jj] = xx * cs - yy * sn;
        hi[jj] = yy * cs + xx * sn;
      }
      uint4v pa = uint4v{ pk2(lo[0],lo[1]), pk2(lo[2],lo[3]), pk2(lo[4],lo[5]), pk2(lo[6],lo[7]) };
      uint4v pb = uint4v{ pk2(hi[0],hi[1]), pk2(hi[2],hi[3]), pk2(hi[4],hi[5]), pk2(hi[6],hi[7]) };
      qf[ii][0] = __builtin_bit_cast(short8, pa);
      qf[ii][1] = __builtin_bit_cast(short8, pb);
    }
  }

  __syncthreads();

  // ------- per-ii pass: QK (causally trimmed) -> base-2 softmax (no max) -> P -------
  short4v P[2][16];
  float   invsum[2];
#pragma unroll
  for (int ii = 0; ii < 2; ++ii) {
    const int tmax = 8 + 2 * wv + ii;        // wave-uniform last live tile
    float4v S[16];
#pragma unroll
    for (int t = 0; t < 16; ++t) {
      if (t <= tmax) {
        short8 a0 = *(const short8*)&Kl[t * 16 + il][qd * 8];
        short8 a1 = *(const short8*)&Kl[t * 16 + il][32 + qd * 8];
        float4v z = {0.f, 0.f, 0.f, 0.f};
        z = MFMA_QK(a0, qf[ii][0], z);
        S[t] = MFMA_QK(a1, qf[ii][1], z);
      }
    }
    float sum = 0.0f;
#pragma unroll
    for (int t = 0; t < 16; ++t) {
      if (t <= tmax) {
        float p0 = __builtin_amdgcn_exp2f(S[t][0]);
        float p1 = __builtin_amdgcn_exp2f(S[t][1]);
        float p2 = __builtin_amdgcn_exp2f(S[t][2]);
        float p3 = __builtin_amdgcn_exp2f(S[t][3]);
        if (t == tmax) {                     // boundary mask: key-in-tile > query-in-tile
          if (qd * 4 + 0 > il) p0 = 0.f;
          if (qd * 4 + 1 > il) p1 = 0.f;
          if (qd * 4 + 2 > il) p2 = 0.f;
          if (qd * 4 + 3 > il) p3 = 0.f;
        }
        sum += (p0 + p1) + (p2 + p3);
        uint2v pw = uint2v{ pk2(p0, p1), pk2(p2, p3) };
        P[ii][t] = __builtin_bit_cast(short4v, pw);
      }
    }
    sum += __shfl_xor(sum, 16);
    sum += __shfl_xor(sum, 32);
    invsum[ii] = __builtin_amdgcn_rcpf(sum);
  }

  // ---------------- PV half 1: keys 0..127 (tiles c=0..7, always live) ----------------
  float4v O[2][4];
#pragma unroll
  for (int ii = 0; ii < 2; ++ii)
#pragma unroll
    for (int dt = 0; dt < 4; ++dt) { float4v z = {0.f,0.f,0.f,0.f}; O[ii][dt] = z; }

#pragma unroll
  for (int c = 0; c < 8; ++c) {
    short4v af[4];
#pragma unroll
    for (int dt = 0; dt < 4; ++dt)
      af[dt] = *(const short4v*)&Vt[c * 4 + qd][dt * 16 + il][0];
#pragma unroll
    for (int dt = 0; dt < 4; ++dt) {
      O[0][dt] = MFMA_PV(af[dt], P[0][c], O[0][dt]);
      O[1][dt] = MFMA_PV(af[dt], P[1][c], O[1][dt]);
    }
  }

  // ---------------- swap V^T buffer to keys 128..255 ----------------
  __syncthreads();                           // all waves done reading half 1
  {
    const int m  = tid & 15;
    const int d0 = m << 2;
#pragma unroll
    for (int pv = 0; pv < 2; ++pv) {
      int chunk = ((tid >> 4) + pv * 16);    // same chunk slot, data = keys 128..255
#pragma unroll
      for (int dd = 0; dd < 4; ++dd) {
        int cc = (dd + m) & 3;
        *(uint2v*)&Vt[chunk][d0 + cc][0] = V2r[pv][dd];
      }
    }
  }
  __syncthreads();

  // ---------------- PV half 2: keys 128..255 (tiles c=8..15, causally trimmed) --------
  const int tmax0 = 8 + 2 * wv;
#pragma unroll
  for (int c = 8; c < 16; ++c) {
    if (c <= tmax0 + 1) {                    // live for at least ii=1
      short4v af[4];
#pragma unroll
      for (int dt = 0; dt < 4; ++dt)
        af[dt] = *(const short4v*)&Vt[(c - 8) * 4 + qd][dt * 16 + il][0];
#pragma unroll
      for (int dt = 0; dt < 4; ++dt) {
        if (c <= tmax0) O[0][dt] = MFMA_PV(af[dt], P[0][c], O[0][dt]);
        O[1][dt] = MFMA_PV(af[dt], P[1][c], O[1][dt]);
      }
    }
  }

  // ---------------- epilogue: fold 1/sum, store ----------------
#pragma unroll
  for (int ii = 0; ii < 2; ++ii) {
    const int n = w * W_ + wv * 32 + ii * 16 + il;
    float* op = outg + base + n * D_;
    const float inv = invsum[ii];
#pragma unroll
    for (int dt = 0; dt < 4; ++dt) {
      float4v o = O[ii][dt];
      o[0] *= inv; o[1] *= inv; o[2] *= inv; o[3] *= inv;
      *(float4v*)(op + dt * 16 + qd * 4) = o;
    }
  }
}

extern "C" void kernel_launch(void* const* d_in, const int* in_sizes, int n_in,
                              void* d_out, int out_size, void* d_ws, size_t ws_size,
                              hipStream_t stream)
{
  const float* q = (const float*)d_in[0];
  const float* k = (const float*)d_in[1];
  const float* v = (const float*)d_in[2];
  float* out = (float*)d_out;
  la_fused<<<dim3(64 * 32), dim3(256), 0, stream>>>(q, k, v, out);
}

// Round 4
// 229.952 us; speedup vs baseline: 1.0955x; 1.0955x over previous
//
#include <hip/hip_runtime.h>
#include <hip/hip_bf16.h>

typedef __attribute__((ext_vector_type(8))) short    short8;
typedef __attribute__((ext_vector_type(4))) short    short4v;
typedef __attribute__((ext_vector_type(4))) float    float4v;
typedef __attribute__((ext_vector_type(2))) unsigned uint2v;
typedef __attribute__((ext_vector_type(4))) unsigned uint4v;

// QK^T: S^T tile = K(16x32) * Q^T(32x16), both frags row-major [pos][d]
#define MFMA_QK(A,B,C) __builtin_amdgcn_mfma_f32_16x16x32_bf16(A,B,C,0,0,0)
// PV: K=16 variant -- B-frag layout (n=lane&15, k=quad*4+jj) == QK C/D layout: zero-shuffle P feed
#define MFMA_PV(A,B,C) __builtin_amdgcn_mfma_f32_16x16x16bf16_1k(A,B,C,0,0,0)

#define N_ 4096
#define D_ 64
#define W_ 128
#define WPB 4   // windows per block: K/V ring reuse + prefetch pipeline
// 0.125 (D^-0.5) * log2(e): folded into Q; softmax runs in base-2 with no max-subtract
#define QSCALE 0.18033688011112042f

static __device__ __forceinline__ unsigned pk2(float a, float b) {
  unsigned ua = __float_as_uint(a) + 0x8000u;   // round-half-up; inputs finite
  unsigned ub = __float_as_uint(b) + 0x8000u;
  return __builtin_amdgcn_perm(ub, ua, 0x07060302u);
}
static __device__ __forceinline__ void rope_sc(float rev, float& sn, float& cs) {
  float fr = __builtin_amdgcn_fractf(rev);      // v_sin/v_cos take revolutions
  sn = __builtin_amdgcn_sinf(fr);
  cs = __builtin_amdgcn_cosf(fr);
}
static __device__ __forceinline__ float invfreq_rev(int idx) {
  // 10000^(-idx/32) / (2*pi);  log2(10000)/32 = 0.41524101186092034
  return __builtin_amdgcn_exp2f(-0.41524101186092034f * (float)idx) * 0.15915494309189535f;
}

__global__ __launch_bounds__(256, 2)
void la_fused(const float* __restrict__ qg, const float* __restrict__ kg,
              const float* __restrict__ vg, float* __restrict__ outg)
{
  // Ring of two 128-key segments; window w: backward half in seg w&1, current in (w+1)&1.
  // K row stride 72 shorts: b128 frag reads 2-way(free); V^T lane-rotated writes 2-way.
  __shared__ __attribute__((aligned(16))) short Kseg[2][128][72];
  __shared__ __attribute__((aligned(16))) short Vt[2][32][68][4];
  // LDS 71,680 B -> 2 blocks/CU (pipeline inside the block supplies the overlap)

  const int blk  = blockIdx.x;
  const int wg   = blk & 7;        // window group: windows wg*4 .. wg*4+3
  const int bh   = blk >> 3;
  const int w0   = wg * WPB;
  const int base = bh * (N_ * D_);
  const int tid  = threadIdx.x;
  const int lane = tid & 63;
  const int wv   = tid >> 6;       // wave owns query rows wv*32..wv*32+31 of each window
  const int il   = lane & 15;
  const int qd   = lane >> 4;

  const float* kb = kg + base;
  const float* vb = vg + base;

  // staging thread mappings (fixed per thread)
  const int kd0 = (tid & 7) << 2;  // K: d-offset 0..28
  const int kjw = tid >> 3;        // K: row-within-32
  const int vm  = tid & 15;        // V: d-quad index
  const int vd0 = vm << 2;
  const int vjc = tid >> 4;        // V: chunk base 0..15
  float kfr[4], qfr[8];
#pragma unroll
  for (int dd = 0; dd < 4; ++dd) kfr[dd] = invfreq_rev(kd0 + dd);
#pragma unroll
  for (int jj = 0; jj < 8; ++jj) qfr[jj] = invfreq_rev(qd * 8 + jj);

  // ---- K staging: RoPE+pack one 32-row unit into Kseg ----
  auto kRow = [&](int seg, int j, float4v a, float4v b, float t, bool pad) {
    uint2v w0v, w1v;
    if (pad) { w0v = uint2v{0xBF80BF80u, 0xBF80BF80u}; w1v = w0v; }
    else {
      float lo[4], hi[4];
#pragma unroll
      for (int dd = 0; dd < 4; ++dd) {
        float sn, cs; rope_sc(t * kfr[dd], sn, cs);
        lo[dd] = a[dd] * cs - b[dd] * sn;
        hi[dd] = b[dd] * cs + a[dd] * sn;
      }
      w0v = uint2v{ pk2(lo[0], lo[1]), pk2(lo[2], lo[3]) };
      w1v = uint2v{ pk2(hi[0], hi[1]), pk2(hi[2], hi[3]) };
    }
    *(uint2v*)&Kseg[seg][j][kd0]      = w0v;
    *(uint2v*)&Kseg[seg][j][kd0 + 32] = w1v;
  };
  auto stageK = [&](int seg, int grow0) {        // direct global->LDS (initial fill)
#pragma unroll
    for (int u = 0; u < 4; ++u) {
      int j = u * 32 + kjw, g = grow0 + j;
      float4v a = {0,0,0,0}, b = {0,0,0,0};
      if (g >= 0) {
        a = *(const float4v*)(kb + g * D_ + kd0);
        b = *(const float4v*)(kb + g * D_ + kd0 + 32);
      }
      kRow(seg, j, a, b, (float)g, g < 0);
    }
  };
  auto vChunk = [&](int seg, int ch, const float4v vv[4]) {
#pragma unroll
    for (int dd = 0; dd < 4; ++dd) {
      int cc = (dd + vm) & 3;                    // lane-rotated: spreads banks
      uint2v pw = uint2v{ pk2(vv[0][cc], vv[1][cc]), pk2(vv[2][cc], vv[3][cc]) };
      *(uint2v*)&Vt[seg][ch][vd0 + cc][0] = pw;
    }
  };
  auto stageV = [&](int seg, int grow0) {        // direct (initial fill)
#pragma unroll
    for (int pvi = 0; pvi < 2; ++pvi) {
      int ch = vjc + pvi * 16, g0 = grow0 + ch * 4;
      float4v vv[4];
      if (g0 < 0) {
        float4v m1 = {-1.f,-1.f,-1.f,-1.f};
#pragma unroll
        for (int rr = 0; rr < 4; ++rr) vv[rr] = m1;
      } else {
#pragma unroll
        for (int rr = 0; rr < 4; ++rr) vv[rr] = *(const float4v*)(vb + (g0 + rr) * D_ + vd0);
      }
      vChunk(seg, ch, vv);
    }
  };

  // ---- Q fragments for window w (no LDS dependency) ----
  short8 qf[2][2];
  auto buildQ = [&](int w) {
#pragma unroll
    for (int ii = 0; ii < 2; ++ii) {
      const int n = w * W_ + wv * 32 + ii * 16 + il;
      const float* qr = qg + base + n * D_ + qd * 8;
      float4v x0 = *(const float4v*)(qr);
      float4v x1 = *(const float4v*)(qr + 4);
      float4v y0 = *(const float4v*)(qr + 32);
      float4v y1 = *(const float4v*)(qr + 36);
      const float t = (float)n;
      float lo[8], hi[8];
#pragma unroll
      for (int jj = 0; jj < 8; ++jj) {
        float xx = ((jj < 4) ? x0[jj & 3] : x1[jj & 3]) * QSCALE;
        float yy = ((jj < 4) ? y0[jj & 3] : y1[jj & 3]) * QSCALE;
        float sn, cs; rope_sc(t * qfr[jj], sn, cs);
        lo[jj] = xx * cs - yy * sn;
        hi[jj] = yy * cs + xx * sn;
      }
      uint4v pa = uint4v{ pk2(lo[0],lo[1]), pk2(lo[2],lo[3]), pk2(lo[4],lo[5]), pk2(lo[6],lo[7]) };
      uint4v pb = uint4v{ pk2(hi[0],hi[1]), pk2(hi[2],hi[3]), pk2(hi[4],hi[5]), pk2(hi[6],hi[7]) };
      qf[ii][0] = __builtin_bit_cast(short8, pa);
      qf[ii][1] = __builtin_bit_cast(short8, pb);
    }
  };

  // ---------------- initial fill: windows w0's backward + current halves ----------------
  stageK(w0 & 1,       w0 * W_ - W_);
  stageK((w0 + 1) & 1, w0 * W_);
  stageV(w0 & 1,       w0 * W_ - W_);
  stageV((w0 + 1) & 1, w0 * W_);
  buildQ(w0);
  __syncthreads();

  float4v pkr[8];   // prefetched K fp32 (next current half)
  float4v pvr[8];   // prefetched V fp32

#pragma unroll
  for (int wi = 0; wi < WPB; ++wi) {
    const int w  = w0 + wi;
    const int sA = w & 1, sB = (w + 1) & 1;
    const bool last = (wi == WPB - 1);

    // -------- issue prefetch of next current half (rows [(w+1)*128, (w+2)*128)) --------
    if (!last) {
      const int grow0 = (w + 1) * W_;
#pragma unroll
      for (int u = 0; u < 4; ++u) {
        int g = grow0 + u * 32 + kjw;
        pkr[2*u]   = *(const float4v*)(kb + g * D_ + kd0);
        pkr[2*u+1] = *(const float4v*)(kb + g * D_ + kd0 + 32);
      }
#pragma unroll
      for (int pvi = 0; pvi < 2; ++pvi) {
        int g0 = grow0 + (vjc + pvi * 16) * 4;
#pragma unroll
        for (int rr = 0; rr < 4; ++rr)
          pvr[pvi*4+rr] = *(const float4v*)(vb + (g0 + rr) * D_ + vd0);
      }
    }

    // -------- QK (causally trimmed) -> base-2 softmax (no max) -> P, streamed --------
    short4v P[2][16];
    float   invsum[2];
#pragma unroll
    for (int ii = 0; ii < 2; ++ii) {
      const int tmax = 8 + 2 * wv + ii;      // wave-uniform last live tile
      float sum = 0.0f;
#pragma unroll
      for (int t = 0; t < 16; ++t) {
        if (t <= tmax) {
          const short* kr = (t < 8) ? &Kseg[sA][t * 16 + il][0]
                                    : &Kseg[sB][(t - 8) * 16 + il][0];
          short8 a0 = *(const short8*)(kr + qd * 8);
          short8 a1 = *(const short8*)(kr + 32 + qd * 8);
          float4v z = {0.f, 0.f, 0.f, 0.f};
          z = MFMA_QK(a0, qf[ii][0], z);
          z = MFMA_QK(a1, qf[ii][1], z);
          float p0 = __builtin_amdgcn_exp2f(z[0]);
          float p1 = __builtin_amdgcn_exp2f(z[1]);
          float p2 = __builtin_amdgcn_exp2f(z[2]);
          float p3 = __builtin_amdgcn_exp2f(z[3]);
          if (t == tmax) {                   // boundary: key-in-tile > query-in-tile
            if (qd * 4 + 0 > il) p0 = 0.f;
            if (qd * 4 + 1 > il) p1 = 0.f;
            if (qd * 4 + 2 > il) p2 = 0.f;
            if (qd * 4 + 3 > il) p3 = 0.f;
          }
          sum += (p0 + p1) + (p2 + p3);
          uint2v pw = uint2v{ pk2(p0, p1), pk2(p2, p3) };
          P[ii][t] = __builtin_bit_cast(short4v, pw);
        }
      }
      sum += __shfl_xor(sum, 16);
      sum += __shfl_xor(sum, 32);
      invsum[ii] = __builtin_amdgcn_rcpf(sum);
    }

    // -------- PV: O^T = V^T * P^T (trimmed) --------
    float4v O[2][4];
#pragma unroll
    for (int ii = 0; ii < 2; ++ii)
#pragma unroll
      for (int dt = 0; dt < 4; ++dt) { float4v z = {0.f,0.f,0.f,0.f}; O[ii][dt] = z; }
    const int cmax0 = 8 + 2 * wv;
#pragma unroll
    for (int c = 0; c < 16; ++c) {
      if (c <= cmax0 + 1) {
        short4v af[4];
#pragma unroll
        for (int dt = 0; dt < 4; ++dt)
          af[dt] = *(const short4v*)&Vt[c < 8 ? sA : sB][(c & 7) * 4 + qd][dt * 16 + il][0];
#pragma unroll
        for (int dt = 0; dt < 4; ++dt) {
          if (c <= cmax0) O[0][dt] = MFMA_PV(af[dt], P[0][c], O[0][dt]);
          O[1][dt] = MFMA_PV(af[dt], P[1][c], O[1][dt]);
        }
      }
    }

    // -------- epilogue: fold 1/sum, store --------
#pragma unroll
    for (int ii = 0; ii < 2; ++ii) {
      const int n = w * W_ + wv * 32 + ii * 16 + il;
      float* op = outg + base + n * D_;
      const float inv = invsum[ii];
#pragma unroll
      for (int dt = 0; dt < 4; ++dt) {
        float4v o = O[ii][dt];
        o[0] *= inv; o[1] *= inv; o[2] *= inv; o[3] *= inv;
        *(float4v*)(op + dt * 16 + qd * 4) = o;
      }
    }

    // -------- commit prefetched K/V into the retiring segment; build next Q --------
    if (!last) {
      __syncthreads();                       // all waves done reading seg sA
      const int grow0 = (w + 1) * W_;
#pragma unroll
      for (int u = 0; u < 4; ++u)
        kRow(sA, u * 32 + kjw, pkr[2*u], pkr[2*u+1], (float)(grow0 + u * 32 + kjw), false);
#pragma unroll
      for (int pvi = 0; pvi < 2; ++pvi) {
        float4v vv[4];
#pragma unroll
        for (int rr = 0; rr < 4; ++rr) vv[rr] = pvr[pvi*4+rr];
        vChunk(sA, vjc + pvi * 16, vv);
      }
      buildQ(w + 1);                         // overlaps other waves' staging
      __syncthreads();
    }
  }
}

extern "C" void kernel_launch(void* const* d_in, const int* in_sizes, int n_in,
                              void* d_out, int out_size, void* d_ws, size_t ws_size,
                              hipStream_t stream)
{
  const float* q = (const float*)d_in[0];
  const float* k = (const float*)d_in[1];
  const float* v = (const float*)d_in[2];
  float* out = (float*)d_out;
  la_fused<<<dim3(64 * 8), dim3(256), 0, stream>>>(q, k, v, out);
}